// Round 19
// baseline (1166.732 us; speedup 1.0000x reference)
//
#include <hip/hip_runtime.h>
#include <hip/hip_bf16.h>

typedef const float* fp32p;

// ---------------- workspace layout (bytes) ----------------
// h1: 64*128*128*16 f32 = 67,108,864 B   @ 0          (part3 [32][2048] aliases once h1 dead)
// h2: 4,194,304 B                        @ 67,108,864 (part1 [32][2048] aliases before conv2; redH after vq)
// di: 4,194,304 B                        @ 71,303,168 (part2 [8][1024] aliases before vq writes)
// scalars @ 75,497,472: bnf float[64]; bnd double[8] @ +256; redE double[1024] @ +320 (ends +8512)
// cnts: uint[4] @ +8512 (zeroed each launch via hipMemsetAsync)
// redH double[4096] @ 67,108,864 (aliases dead h2)

__device__ __forceinline__ float4 f4fma(float s, float4 w, float4 a){
  a.x = fmaf(s,w.x,a.x); a.y = fmaf(s,w.y,a.y);
  a.z = fmaf(s,w.z,a.z); a.w = fmaf(s,w.w,a.w);
  return a;
}

__device__ __forceinline__ float dot4acc(float4 d, float4 w, float a){
  a = fmaf(d.x,w.x,a); a = fmaf(d.y,w.y,a);
  a = fmaf(d.z,w.z,a); a = fmaf(d.w,w.w,a);
  return a;
}

__device__ __forceinline__ double block_sum_all_d(double v, double* sm){
  #pragma unroll
  for (int m=1;m<64;m<<=1) v += __shfl_xor(v, m, 64);
  int lane = threadIdx.x & 63, wid = threadIdx.x >> 6;
  if (lane==0) sm[wid] = v;
  __syncthreads();
  return sm[0]+sm[1]+sm[2]+sm[3];
}

// fused reduce bodies (identical math/order to the old k_redf/k_redd kernels)
__device__ void tail_redf(const float* __restrict__ part, int N, int nch, fp32p g, fp32p be,
                          double cnt, float* __restrict__ sc, float* __restrict__ sh, double* smd){
  int tid = threadIdx.x;
  for (int c=0;c<nch;c++){
    double s=0.0,q=0.0;
    for (int i=tid;i<N;i+=256){ s += (double)part[c*N+i]; q += (double)part[(nch+c)*N+i]; }
    s = block_sum_all_d(s, smd); __syncthreads();
    q = block_sum_all_d(q, smd);
    if (tid==0){
      double m = s/cnt;
      double var = q/cnt - m*m;
      double sd = (double)g[c] / sqrt(var + 1e-5);
      sc[c] = (float)sd;
      sh[c] = (float)((double)be[c] - m*sd);
    }
    __syncthreads();
  }
}

__device__ void tail_redd(const float* __restrict__ part, int N, int nch, fp32p g, fp32p be,
                          double cnt, double* __restrict__ sc, double* __restrict__ sh, double* smd){
  int tid = threadIdx.x;
  for (int c=0;c<nch;c++){
    double s=0.0,q=0.0;
    for (int i=tid;i<N;i+=256){ s += (double)part[c*N+i]; q += (double)part[(nch+c)*N+i]; }
    s = block_sum_all_d(s, smd); __syncthreads();
    q = block_sum_all_d(q, smd);
    if (tid==0){
      double m = s/cnt;
      double var = q/cnt - m*m;
      double sd = (double)g[c] / sqrt(var + 1e-5);
      sc[c] = sd;
      sh[c] = (double)be[c] - m*sd;
    }
    __syncthreads();
  }
}

// ---------------- K1: conv1 1->16 k4 s2 p1, LDS-tiled, 2 px/thread + stats + fused BN1 reduce
__global__ __launch_bounds__(256) void k_conv1v2(fp32p x, fp32p w1, fp32p b1,
                                                 float* __restrict__ h1, float* __restrict__ part,
                                                 fp32p g1, fp32p be1,
                                                 float* __restrict__ sc1o, float* __restrict__ sh1o,
                                                 unsigned* __restrict__ cnt){
  __shared__ float sx[34][67];
  __shared__ float sw[16][16];   // [tap][co]
  __shared__ float sb[16];
  __shared__ float red[4][32];
  __shared__ double smd[4];
  __shared__ unsigned lastFlag;
  int tid = threadIdx.x;
  { int co = tid & 15, tap = tid >> 4;
    sw[tap][co] = w1[co*16 + tap];
    if (tid < 16) sb[tid] = b1[tid]; }
  int b = blockIdx.x;
  int n = b>>5, t = b&31, ty = t>>2, tx = t&3;
  int OY = ty*16, OX = tx*32;
  int gy0 = OY*2-1, gx0 = OX*2-1;
  const float* xb = x + n*65536;
  for (int p=tid; p<2244; p+=256){          // 34 x 66 window
    int r = p/66, c = p - r*66;
    int gy = gy0+r, gx = gx0+c;
    sx[r][c] = ((unsigned)gy < 256u && (unsigned)gx < 256u) ? xb[gy*256+gx] : 0.f;
  }
  __syncthreads();
  int oyl = tid>>4, oxl = tid&15;           // px pair: (oyl, 2*oxl), (oyl, 2*oxl+1)
  float4 a00 = *(float4*)&sb[0], a01 = *(float4*)&sb[4],
         a02 = *(float4*)&sb[8], a03 = *(float4*)&sb[12];
  float4 a10 = a00, a11 = a01, a12 = a02, a13 = a03;
  #pragma unroll
  for (int ky=0; ky<4; ky++){
    const float* sxr = &sx[oyl*2+ky][4*oxl];
    #pragma unroll
    for (int kx=0; kx<4; kx++){
      const float4* wr = (const float4*)&sw[ky*4+kx][0];
      float4 w0 = wr[0], w1v = wr[1], w2 = wr[2], w3 = wr[3];
      float v0 = sxr[kx];
      a00 = f4fma(v0, w0, a00); a01 = f4fma(v0, w1v, a01);
      a02 = f4fma(v0, w2, a02); a03 = f4fma(v0, w3, a03);
      float v1 = sxr[2+kx];
      a10 = f4fma(v1, w0, a10); a11 = f4fma(v1, w1v, a11);
      a12 = f4fma(v1, w2, a12); a13 = f4fma(v1, w3, a13);
    }
  }
  int gid = (n*128+OY+oyl)*128 + OX + 2*oxl;
  float4* o = (float4*)&h1[(unsigned)gid*16u];
  o[0]=a00; o[1]=a01; o[2]=a02; o[3]=a03;
  o[4]=a10; o[5]=a11; o[6]=a12; o[7]=a13;
  float f0[16], f1[16];
  *(float4*)&f0[0]=a00; *(float4*)&f0[4]=a01; *(float4*)&f0[8]=a02; *(float4*)&f0[12]=a03;
  *(float4*)&f1[0]=a10; *(float4*)&f1[4]=a11; *(float4*)&f1[8]=a12; *(float4*)&f1[12]=a13;
  int lane = tid & 63, wid = tid >> 6;
  #pragma unroll
  for (int c=0;c<16;c++){
    float s = f0[c] + f1[c];
    float q = fmaf(f0[c],f0[c], f1[c]*f1[c]);
    #pragma unroll
    for (int m=1;m<64;m<<=1){ s += __shfl_xor(s,m,64); q += __shfl_xor(q,m,64); }
    if (lane==0){ red[wid][c]=s; red[wid][16+c]=q; }
  }
  __syncthreads();
  if (tid<32){
    float v = red[0][tid]+red[1][tid]+red[2][tid]+red[3][tid];
    part[tid*2048 + blockIdx.x] = v;
  }
  // ---- ticket: last block reduces BN1 stats -> sc1/sh1
  __threadfence();
  __syncthreads();
  if (tid==0) lastFlag = (atomicAdd(cnt, 1u) == gridDim.x-1) ? 1u : 0u;
  __syncthreads();
  if (lastFlag){
    __threadfence();
    tail_redf(part, 2048, 16, g1, be1, 1048576.0, sc1o, sh1o, smd);
  }
}

// ---------------- K2: BN1+ReLU fused read, conv2 16->4 k4 s2 p1 + stats + fused BN2 reduce
__global__ __launch_bounds__(256) void k_conv2(const float* __restrict__ h1, fp32p w2, fp32p b2,
    const float* __restrict__ sc1, const float* __restrict__ sh1,
    float* __restrict__ h2, float* __restrict__ part,
    fp32p g2, fp32p be2, double* __restrict__ bnd, unsigned* __restrict__ cnt){
  __shared__ float sw[16][16][4];   // [tap][ci][co]
  __shared__ float sb[4];
  __shared__ float red[4][8];
  __shared__ double smd[4];
  __shared__ unsigned lastFlag;
  int tid = threadIdx.x;
  for (int j=tid;j<1024;j+=256){
    int co=j&3, ci=(j>>2)&15, tap=j>>6;
    sw[tap][ci][co] = w2[(co*16+ci)*16 + tap];
  }
  if (tid<4) sb[tid]=b2[tid];
  __syncthreads();
  float sc[16], sh[16];
  #pragma unroll
  for (int c=0;c<16;c++){ sc[c]=sc1[c]; sh[c]=sh1[c]; }
  int gid = blockIdx.x*256+tid;
  int ox = gid&63, oy=(gid>>6)&63, n=gid>>12;
  float4 acc = *(float4*)&sb[0];
  #pragma unroll
  for (int ky=0;ky<4;ky++){
    int iy = oy*2-1+ky;
    if ((unsigned)iy >= 128u) continue;
    #pragma unroll
    for (int kx=0;kx<4;kx++){
      int ix = ox*2-1+kx;
      if ((unsigned)ix >= 128u) continue;
      const float4* hp = (const float4*)&h1[((n*128+iy)*128+ix)*16];
      const float4* wt = (const float4*)&sw[ky*4+kx][0][0];
      #pragma unroll
      for (int c4=0;c4<4;c4++){
        float4 hv = hp[c4];
        float v;
        v = fmaxf(fmaf(hv.x, sc[c4*4+0], sh[c4*4+0]), 0.f); acc = f4fma(v, wt[c4*4+0], acc);
        v = fmaxf(fmaf(hv.y, sc[c4*4+1], sh[c4*4+1]), 0.f); acc = f4fma(v, wt[c4*4+1], acc);
        v = fmaxf(fmaf(hv.z, sc[c4*4+2], sh[c4*4+2]), 0.f); acc = f4fma(v, wt[c4*4+2], acc);
        v = fmaxf(fmaf(hv.w, sc[c4*4+3], sh[c4*4+3]), 0.f); acc = f4fma(v, wt[c4*4+3], acc);
      }
    }
  }
  *(float4*)&h2[(unsigned)gid*4u] = acc;
  float aa[4]; *(float4*)&aa[0] = acc;
  int lane = tid & 63, wid = tid >> 6;
  #pragma unroll
  for (int c=0;c<4;c++){
    float s = aa[c], q = aa[c]*aa[c];
    #pragma unroll
    for (int m=1;m<64;m<<=1){ s += __shfl_xor(s,m,64); q += __shfl_xor(q,m,64); }
    if (lane==0){ red[wid][c]=s; red[wid][4+c]=q; }
  }
  __syncthreads();
  if (tid<8){
    float v = red[0][tid]+red[1][tid]+red[2][tid]+red[3][tid];
    part[tid*1024 + blockIdx.x] = v;
  }
  // ---- ticket: last block reduces BN2 stats -> bnd (double, argmin-critical)
  __threadfence();
  __syncthreads();
  if (tid==0) lastFlag = (atomicAdd(cnt, 1u) == gridDim.x-1) ? 1u : 0u;
  __syncthreads();
  if (lastFlag){
    __threadfence();
    tail_redd(part, 1024, 4, g2, be2, 262144.0, bnd, bnd+4, smd);
  }
}

// ---------------- K3: BN2(d)+ReLU -> pre 1x1 -> VQ argmin (fp64) -> loss -> post 1x1 -> di
__global__ __launch_bounds__(256) void k_vq(const float* __restrict__ h2,
    const double* __restrict__ bnd,
    fp32p wpre, fp32p bpre, fp32p emb, fp32p wpost, fp32p bpost,
    float* __restrict__ di, double* __restrict__ redE){
  __shared__ double se[128];
  __shared__ double sm[4];
  int tid = threadIdx.x;
  if (tid < 128) se[tid] = (double)emb[tid];
  __syncthreads();
  double sc[4], sh[4];
  #pragma unroll
  for (int c=0;c<4;c++){ sc[c]=bnd[c]; sh[c]=bnd[4+c]; }
  double wa0=wpre[0], wa1=wpre[1], wa2=wpre[2], wa3=wpre[3];
  double wb0=wpre[4], wb1=wpre[5], wb2=wpre[6], wb3=wpre[7];
  double bp0=bpre[0], bp1=bpre[1];
  double p00=wpost[0], p01=wpost[1];
  double p10=wpost[2], p11=wpost[3];
  double p20=wpost[4], p21=wpost[5];
  double p30=wpost[6], p31=wpost[7];
  double bq0=bpost[0], bq1=bpost[1], bq2=bpost[2], bq3=bpost[3];
  int p = blockIdx.x*256 + tid;             // 262144 threads, 1 pixel each
  float4 hv = *(const float4*)&h2[(unsigned)p*4u];
  double h0 = fmax(fma((double)hv.x, sc[0], sh[0]), 0.0);
  double h1v = fmax(fma((double)hv.y, sc[1], sh[1]), 0.0);
  double h2v = fmax(fma((double)hv.z, sc[2], sh[2]), 0.0);
  double h3v = fmax(fma((double)hv.w, sc[3], sh[3]), 0.0);
  double z0 = bp0 + wa0*h0 + wa1*h1v + wa2*h2v + wa3*h3v;
  double z1 = bp1 + wb0*h0 + wb1*h1v + wb2*h2v + wb3*h3v;
  double best = 1e300; int bi = 0;
  #pragma unroll
  for (int k=0;k<64;k++){
    double d0 = z0 - se[2*k], d1 = z1 - se[2*k+1];
    double d = fma(d0,d0, d1*d1);
    if (d < best){ best = d; bi = k; }      // first-min tie rule == argmin
  }
  double qv0 = se[2*bi], qv1 = se[2*bi+1];
  double e0 = qv0-z0, e1 = qv1-z1;
  double lsum = fma(e0,e0, e1*e1);
  float4 o;
  o.x = (float)(fma(p00,qv0, fma(p01,qv1, bq0)));
  o.y = (float)(fma(p10,qv0, fma(p11,qv1, bq1)));
  o.z = (float)(fma(p20,qv0, fma(p21,qv1, bq2)));
  o.w = (float)(fma(p30,qv0, fma(p31,qv1, bq3)));
  *(float4*)&di[(unsigned)p*4u] = o;
  double tot = block_sum_all_d(lsum, sm);
  if (tid==0) redE[blockIdx.x] = tot;
}

// ---------------- K4: BN3 stats via convT1 recompute, 2 px/thread + fused BN3 reduce
__global__ __launch_bounds__(256) void k_stats3v2(const float* __restrict__ di, fp32p wd1, fp32p bd1,
                                                  float* __restrict__ part,
                                                  fp32p g3, fp32p be3,
                                                  float* __restrict__ sc3o, float* __restrict__ sh3o,
                                                  unsigned* __restrict__ cnt){
  __shared__ float sw[16][4][16];   // [tap][ci][co]
  __shared__ float sb[16];
  __shared__ float red[4][32];
  __shared__ double smd[4];
  __shared__ unsigned lastFlag;
  int tid = threadIdx.x;
  for (int j=tid; j<1024; j+=256){
    int co = j & 15, ci = (j>>4)&3, tap = j>>6;
    sw[tap][ci][co] = wd1[(ci*16+co)*16 + tap];
  }
  if (tid<16) sb[tid] = bd1[tid];
  __syncthreads();
  int gid = blockIdx.x*256 + tid;          // 2048 blocks: 64 xpair x 128 y x 64 n
  int k  = gid & 63;                       // = lane -> coalesced ix
  int oy = (gid >> 6) & 127;               // wave-uniform
  int n  = gid >> 13;
  float4 e0 = *(float4*)&sb[0], e1 = *(float4*)&sb[4],
         e2 = *(float4*)&sb[8], e3 = *(float4*)&sb[12];
  float4 o0 = e0, o1 = e1, o2 = e2, o3 = e3;
  int py = (oy+1)&1;                       // wave-uniform
  #pragma unroll
  for (int jt=0;jt<2;jt++){
    int ky = py + 2*jt;
    int iy = (oy+1-ky) >> 1;
    if ((unsigned)iy >= 64u) continue;     // uniform branch
    const float4* drow = (const float4*)&di[((n*64+iy)*64)*4];
    float4 dm = (k>=1) ? drow[k-1] : make_float4(0.f,0.f,0.f,0.f);
    float4 d0 = drow[k];
    float4 dp = (k<63) ? drow[k+1] : make_float4(0.f,0.f,0.f,0.f);
    // even px (ox=2k, pxx=1): it=0 -> kx=1 (ix=k, d0); it=1 -> kx=3 (ix=k-1, dm)
    {
      int tap = ky*4 + 1;
      float vv[4] = {d0.x, d0.y, d0.z, d0.w};
      #pragma unroll
      for (int ci=0;ci<4;ci++){
        const float4* wr = (const float4*)&sw[tap][ci][0];
        e0 = f4fma(vv[ci], wr[0], e0); e1 = f4fma(vv[ci], wr[1], e1);
        e2 = f4fma(vv[ci], wr[2], e2); e3 = f4fma(vv[ci], wr[3], e3);
      }
      tap = ky*4 + 3;
      float vm[4] = {dm.x, dm.y, dm.z, dm.w};
      #pragma unroll
      for (int ci=0;ci<4;ci++){
        const float4* wr = (const float4*)&sw[tap][ci][0];
        e0 = f4fma(vm[ci], wr[0], e0); e1 = f4fma(vm[ci], wr[1], e1);
        e2 = f4fma(vm[ci], wr[2], e2); e3 = f4fma(vm[ci], wr[3], e3);
      }
    }
    // odd px (ox=2k+1, pxx=0): it=0 -> kx=0 (ix=k+1, dp); it=1 -> kx=2 (ix=k, d0)
    {
      int tap = ky*4 + 0;
      float vp[4] = {dp.x, dp.y, dp.z, dp.w};
      #pragma unroll
      for (int ci=0;ci<4;ci++){
        const float4* wr = (const float4*)&sw[tap][ci][0];
        o0 = f4fma(vp[ci], wr[0], o0); o1 = f4fma(vp[ci], wr[1], o1);
        o2 = f4fma(vp[ci], wr[2], o2); o3 = f4fma(vp[ci], wr[3], o3);
      }
      tap = ky*4 + 2;
      float v0[4] = {d0.x, d0.y, d0.z, d0.w};
      #pragma unroll
      for (int ci=0;ci<4;ci++){
        const float4* wr = (const float4*)&sw[tap][ci][0];
        o0 = f4fma(v0[ci], wr[0], o0); o1 = f4fma(v0[ci], wr[1], o1);
        o2 = f4fma(v0[ci], wr[2], o2); o3 = f4fma(v0[ci], wr[3], o3);
      }
    }
  }
  float fe[16], fo[16];
  *(float4*)&fe[0]=e0; *(float4*)&fe[4]=e1; *(float4*)&fe[8]=e2; *(float4*)&fe[12]=e3;
  *(float4*)&fo[0]=o0; *(float4*)&fo[4]=o1; *(float4*)&fo[8]=o2; *(float4*)&fo[12]=o3;
  int lane = tid & 63, wid = tid >> 6;
  #pragma unroll
  for (int c=0;c<16;c++){
    float s = fe[c] + fo[c];
    float q = fmaf(fe[c],fe[c], fo[c]*fo[c]);
    #pragma unroll
    for (int m=1;m<64;m<<=1){ s += __shfl_xor(s,m,64); q += __shfl_xor(q,m,64); }
    if (lane==0){ red[wid][c]=s; red[wid][16+c]=q; }
  }
  __syncthreads();
  if (tid<32){
    float v = red[0][tid]+red[1][tid]+red[2][tid]+red[3][tid];
    part[tid*2048 + blockIdx.x] = v;
  }
  // ---- ticket: last block reduces BN3 stats -> sc3/sh3
  __threadfence();
  __syncthreads();
  if (tid==0) lastFlag = (atomicAdd(cnt, 1u) == gridDim.x-1) ? 1u : 0u;
  __syncthreads();
  if (lastFlag){
    __threadfence();
    tail_redf(part, 2048, 16, g3, be3, 1048576.0, sc3o, sh3o, smd);
  }
}

// ---------------- K5: fused convT1 -> BN3+ReLU (LDS) -> convT2 -> tanh -> out + recon loss
// Phase A: wave-uniform parity classes. Phase B: q-major shared-column loads.
// Last block computes the final loss (old k_final body).
__global__ __launch_bounds__(256) void k_fuseT8(const float* __restrict__ di,
    fp32p wd1, fp32p bd1, fp32p wd2, fp32p bd2,
    const float* __restrict__ sc3, const float* __restrict__ sh3,
    fp32p x, float* __restrict__ out, double* __restrict__ redH,
    const double* __restrict__ redE, int out_size, unsigned* __restrict__ cnt){
  __shared__ float swt[1024];  // convT1 weights [ky][kx][ci4][co16]
  __shared__ float sb1[16];
  __shared__ float sw2[256];   // convT2 weights [ky][kx][ci16]
  __shared__ float h3q[4][18][19][4];
  __shared__ double smd[4];
  __shared__ unsigned lastFlag;
  int tid = threadIdx.x;
  for (int j=tid; j<1024; j+=256){
    int co = j & 15, ci = (j>>4)&3, kx = (j>>6)&3, ky = j>>8;
    swt[j] = wd1[((ci*16+co)*4+ky)*4+kx];
  }
  { int ci = tid & 15, kx = (tid>>4)&3, ky = tid>>6;
    sw2[tid] = wd2[ci*16 + ky*4 + kx]; }
  if (tid<16) sb1[tid] = bd1[tid];
  float s3[16], h3s[16];
  #pragma unroll
  for (int c=0;c<16;c++){ s3[c]=sc3[c]; h3s[c]=sh3[c]; }
  int b = blockIdx.x;
  int n = b>>6, ty=(b>>3)&7, tx=b&7;
  int OY=ty*32, OX=tx*32;
  int R0=ty*16-1, C0=tx*16-1;
  __syncthreads();
  // Phase A: 18x18 h3 tile by wave-uniform parity class: cls = tid>>6 (one class/wave)
  int clsA = tid >> 6;
  int prA = clsA >> 1, pcA = clsA & 1;
  for (int it2=0; it2<2; it2++){
    int idx = (tid & 63) + it2*64;
    if (idx < 81){
      int u = idx/9, v = idx - u*9;
      int rr = 2*u + prA, cc = 2*v + pcA;
      int r = R0 + rr, c = C0 + cc;
      float vo[16];
      if ((unsigned)r < 128u && (unsigned)c < 128u){
        float acc[16];
        #pragma unroll
        for (int ch=0;ch<16;ch++) acc[ch]=sb1[ch];
        #pragma unroll
        for (int j=0;j<2;j++){
          int iy = ty*8 + u - j;
          if ((unsigned)iy >= 64u) continue;
          #pragma unroll
          for (int i=0;i<2;i++){
            int ix = tx*8 + v - i;
            if ((unsigned)ix >= 64u) continue;
            float4 dv = *(const float4*)&di[((n*64+iy)*64+ix)*4];
            const float* wb = &swt[(((prA+2*j)*4+(pcA+2*i))*4)*16];  // broadcast
            float vv[4] = {dv.x, dv.y, dv.z, dv.w};
            #pragma unroll
            for (int ci=0;ci<4;ci++){
              #pragma unroll
              for (int co=0;co<16;co++)
                acc[co] = fmaf(vv[ci], wb[ci*16+co], acc[co]);
            }
          }
        }
        #pragma unroll
        for (int ch=0;ch<16;ch++) vo[ch] = fmaxf(fmaf(acc[ch], s3[ch], h3s[ch]), 0.f);
      } else {
        #pragma unroll
        for (int ch=0;ch<16;ch++) vo[ch]=0.f;
      }
      #pragma unroll
      for (int q=0;q<4;q++)
        *(float4*)&h3q[q][rr][cc][0] = make_float4(vo[4*q],vo[4*q+1],vo[4*q+2],vo[4*q+3]);
    }
  }
  __syncthreads();
  // Phase B: q-major, shared columns.
  int lane = tid & 63, wv = tid >> 6;
  int ri = lane >> 3, tc = lane & 7;
  int row = (wv>>1)*16 + ri*2 + (wv&1);
  int oy = OY + row, ox0 = OX + tc*4;
  int py = (oy+1)&1;                        // wave-uniform
  int rr0 = ((oy + 1 - py) >> 1) - R0;      // in [1,17]; rr0-1 in [0,16]
  int c0 = tc*2;
  float bias = bd2[0];
  float a0=bias, a1=bias, a2=bias, a3=bias;
  #pragma unroll
  for (int q=0;q<4;q++){
    #pragma unroll
    for (int j=0;j<2;j++){
      int rr = rr0 - j;
      int kyb = (py + 2*j)*4;
      float4 d0 = *(float4*)&h3q[q][rr][c0+0][0];
      float4 d1 = *(float4*)&h3q[q][rr][c0+1][0];
      float4 d2 = *(float4*)&h3q[q][rr][c0+2][0];
      float4 d3 = *(float4*)&h3q[q][rr][c0+3][0];
      {
        float4 wA = *(float4*)&sw2[(kyb+1)*16 + q*4];   // broadcast
        float4 wB = *(float4*)&sw2[(kyb+3)*16 + q*4];
        a0 = dot4acc(d1, wA, a0); a0 = dot4acc(d0, wB, a0);
        a2 = dot4acc(d2, wA, a2); a2 = dot4acc(d1, wB, a2);
      }
      {
        float4 wA = *(float4*)&sw2[(kyb+0)*16 + q*4];
        float4 wB = *(float4*)&sw2[(kyb+2)*16 + q*4];
        a1 = dot4acc(d2, wA, a1); a1 = dot4acc(d1, wB, a1);
        a3 = dot4acc(d3, wA, a3); a3 = dot4acc(d2, wB, a3);
      }
    }
  }
  int base = (n*256+oy)*256 + ox0;
  float4 xv = *(const float4*)&x[base];
  float av[4] = {a0,a1,a2,a3};
  float r4[4];
  double rsum = 0.0;
  #pragma unroll
  for (int k=0;k<4;k++){
    float e = __expf(2.f*av[k]);
    float t = 1.f - 2.f/(e+1.f);            // tanh
    r4[k] = t;
    float xd = (k==0?xv.x:k==1?xv.y:k==2?xv.z:xv.w);
    double dd = (double)xd - (double)t;
    rsum = fma(dd,dd,rsum);
  }
  *(float4*)&out[base] = make_float4(r4[0],r4[1],r4[2],r4[3]);
  double tot = block_sum_all_d(rsum, smd);
  if (tid==0) redH[b] = tot;
  // ---- ticket: last block computes the final loss (old k_final body)
  __threadfence();
  __syncthreads();
  if (tid==0) lastFlag = (atomicAdd(cnt, 1u) == gridDim.x-1) ? 1u : 0u;
  __syncthreads();
  if (lastFlag){
    __threadfence();
    double a = 0.0;
    for (int i=tid;i<1024;i+=256) a += redE[i];
    double bb = 0.0;
    for (int i=tid;i<4096;i+=256) bb += redH[i];
    __syncthreads();
    double ta = block_sum_all_d(a, smd);
    __syncthreads();
    double tb = block_sum_all_d(bb, smd);
    if (tid==0){
      double loss = 1.2*ta/524288.0 + tb/4194304.0;  // (1+BETA)*mean((q-z)^2) + recon_mean
      out[out_size-1] = (float)loss;
    }
  }
}

extern "C" void kernel_launch(void* const* d_in, const int* in_sizes, int n_in,
                              void* d_out, int out_size, void* d_ws, size_t ws_size,
                              hipStream_t stream) {
  (void)ws_size;
  int I[20];
  for (int i=0;i<20;i++) I[i]=i;
  if (n_in >= 20 && in_sizes[0] != 4194304 && in_sizes[19] == 4194304){
    static const int remap[20] = {19,13,0,10,4,14,1,11,5,18,8,9,17,7,15,2,12,6,16,3};
    for (int i=0;i<20;i++) I[i]=remap[i];
  }
  fp32p x    = (fp32p)d_in[I[0]];
  fp32p w1   = (fp32p)d_in[I[1]],  b1 = (fp32p)d_in[I[2]],  g1 = (fp32p)d_in[I[3]],  be1 = (fp32p)d_in[I[4]];
  fp32p w2   = (fp32p)d_in[I[5]],  b2 = (fp32p)d_in[I[6]],  g2 = (fp32p)d_in[I[7]],  be2 = (fp32p)d_in[I[8]];
  fp32p wpre = (fp32p)d_in[I[9]],  bpre = (fp32p)d_in[I[10]], emb = (fp32p)d_in[I[11]];
  fp32p wpost= (fp32p)d_in[I[12]], bpost= (fp32p)d_in[I[13]];
  fp32p wd1  = (fp32p)d_in[I[14]], bd1 = (fp32p)d_in[I[15]], g3 = (fp32p)d_in[I[16]], be3 = (fp32p)d_in[I[17]];
  fp32p wd2  = (fp32p)d_in[I[18]], bd2 = (fp32p)d_in[I[19]];

  char* wsb = (char*)d_ws;
  float* h1    = (float*)(wsb);
  float* h2    = (float*)(wsb + 67108864);
  float* di    = (float*)(wsb + 71303168);
  float* bnf   = (float*)(wsb + 75497472);         // sc1,sh1,sc3,sh3
  double* bnd  = (double*)(wsb + 75497728);        // sc2d[4], sh2d[4]
  double* redE = (double*)(wsb + 75497792);        // 1024 doubles -> ends at +8512
  unsigned* cnts = (unsigned*)(wsb + 75497472 + 8512);  // 4 uints
  double* redH = (double*)(wsb + 67108864);        // aliases h2 (dead after vq)
  float* part1 = (float*)(wsb + 67108864);         // aliases h2 (consumed before conv2 writes)
  float* part2 = (float*)(wsb + 71303168);         // aliases di (consumed before vq writes)
  float* part3 = (float*)(wsb);                    // aliases h1 (h1 dead after conv2)
  float* sc1 = bnf, *sh1 = bnf+16, *sc3 = bnf+32, *sh3 = bnf+48;
  float* out = (float*)d_out;

  hipMemsetAsync(cnts, 0, 16, stream);
  k_conv1v2 <<<2048,256,0,stream>>>(x, w1, b1, h1, part1, g1, be1, sc1, sh1, cnts+0);
  k_conv2   <<<1024,256,0,stream>>>(h1, w2, b2, sc1, sh1, h2, part2, g2, be2, bnd, cnts+1);
  k_vq      <<<1024,256,0,stream>>>(h2, bnd, wpre, bpre, emb, wpost, bpost, di, redE);
  k_stats3v2<<<2048,256,0,stream>>>(di, wd1, bd1, part3, g3, be3, sc3, sh3, cnts+2);
  k_fuseT8  <<<4096,256,0,stream>>>(di, wd1, bd1, wd2, bd2, sc3, sh3, x, out, redH,
                                    redE, out_size, cnts+3);
}

// Round 20
// 183.740 us; speedup vs baseline: 6.3499x; 6.3499x over previous
//
#include <hip/hip_runtime.h>
#include <hip/hip_bf16.h>

typedef const float* fp32p;

// ---------------- workspace layout (bytes) ----------------
// h1: 64*128*128*16 f32 = 67,108,864 B   @ 0          (part3 [32][2048] aliases once h1 dead)
// h2: 4,194,304 B                        @ 67,108,864 (part1 [32][2048] aliases before conv2; redH after vq)
// di: 4,194,304 B                        @ 71,303,168 (part2 [8][1024] aliases before vq writes)
// scalars @ 75,497,472: bnf float[64]; bnd double[8] @ +256; redE double[1024] @ +320
// redH double[4096] @ 67,108,864 (aliases dead h2)

__device__ __forceinline__ float4 f4fma(float s, float4 w, float4 a){
  a.x = fmaf(s,w.x,a.x); a.y = fmaf(s,w.y,a.y);
  a.z = fmaf(s,w.z,a.z); a.w = fmaf(s,w.w,a.w);
  return a;
}

__device__ __forceinline__ float dot4acc(float4 d, float4 w, float a){
  a = fmaf(d.x,w.x,a); a = fmaf(d.y,w.y,a);
  a = fmaf(d.z,w.z,a); a = fmaf(d.w,w.w,a);
  return a;
}

__device__ __forceinline__ double block_sum_all_d(double v, double* sm){
  #pragma unroll
  for (int m=1;m<64;m<<=1) v += __shfl_xor(v, m, 64);
  int lane = threadIdx.x & 63, wid = threadIdx.x >> 6;
  if (lane==0) sm[wid] = v;
  __syncthreads();
  return sm[0]+sm[1]+sm[2]+sm[3];
}

// ---------------- K1: conv1 1->16 k4 s2 p1, LDS-tiled, 2 px/thread + fused stats partials
__global__ __launch_bounds__(256) void k_conv1v2(fp32p x, fp32p w1, fp32p b1,
                                                 float* __restrict__ h1, float* __restrict__ part){
  __shared__ float sx[34][67];
  __shared__ float sw[16][16];   // [tap][co]
  __shared__ float sb[16];
  __shared__ float red[4][32];
  int tid = threadIdx.x;
  { int co = tid & 15, tap = tid >> 4;
    sw[tap][co] = w1[co*16 + tap];
    if (tid < 16) sb[tid] = b1[tid]; }
  int b = blockIdx.x;
  int n = b>>5, t = b&31, ty = t>>2, tx = t&3;
  int OY = ty*16, OX = tx*32;
  int gy0 = OY*2-1, gx0 = OX*2-1;
  const float* xb = x + n*65536;
  for (int p=tid; p<2244; p+=256){          // 34 x 66 window
    int r = p/66, c = p - r*66;
    int gy = gy0+r, gx = gx0+c;
    sx[r][c] = ((unsigned)gy < 256u && (unsigned)gx < 256u) ? xb[gy*256+gx] : 0.f;
  }
  __syncthreads();
  int oyl = tid>>4, oxl = tid&15;           // px pair: (oyl, 2*oxl), (oyl, 2*oxl+1)
  float4 a00 = *(float4*)&sb[0], a01 = *(float4*)&sb[4],
         a02 = *(float4*)&sb[8], a03 = *(float4*)&sb[12];
  float4 a10 = a00, a11 = a01, a12 = a02, a13 = a03;
  #pragma unroll
  for (int ky=0; ky<4; ky++){
    const float* sxr = &sx[oyl*2+ky][4*oxl];
    #pragma unroll
    for (int kx=0; kx<4; kx++){
      const float4* wr = (const float4*)&sw[ky*4+kx][0];
      float4 w0 = wr[0], w1v = wr[1], w2 = wr[2], w3 = wr[3];
      float v0 = sxr[kx];
      a00 = f4fma(v0, w0, a00); a01 = f4fma(v0, w1v, a01);
      a02 = f4fma(v0, w2, a02); a03 = f4fma(v0, w3, a03);
      float v1 = sxr[2+kx];
      a10 = f4fma(v1, w0, a10); a11 = f4fma(v1, w1v, a11);
      a12 = f4fma(v1, w2, a12); a13 = f4fma(v1, w3, a13);
    }
  }
  int gid = (n*128+OY+oyl)*128 + OX + 2*oxl;
  float4* o = (float4*)&h1[(unsigned)gid*16u];
  o[0]=a00; o[1]=a01; o[2]=a02; o[3]=a03;
  o[4]=a10; o[5]=a11; o[6]=a12; o[7]=a13;
  float f0[16], f1[16];
  *(float4*)&f0[0]=a00; *(float4*)&f0[4]=a01; *(float4*)&f0[8]=a02; *(float4*)&f0[12]=a03;
  *(float4*)&f1[0]=a10; *(float4*)&f1[4]=a11; *(float4*)&f1[8]=a12; *(float4*)&f1[12]=a13;
  int lane = tid & 63, wid = tid >> 6;
  #pragma unroll
  for (int c=0;c<16;c++){
    float s = f0[c] + f1[c];
    float q = fmaf(f0[c],f0[c], f1[c]*f1[c]);
    #pragma unroll
    for (int m=1;m<64;m<<=1){ s += __shfl_xor(s,m,64); q += __shfl_xor(q,m,64); }
    if (lane==0){ red[wid][c]=s; red[wid][16+c]=q; }
  }
  __syncthreads();
  if (tid<32){
    float v = red[0][tid]+red[1][tid]+red[2][tid]+red[3][tid];
    part[tid*2048 + blockIdx.x] = v;
  }
}

// ---------------- reduce partials -> float scale/shift (fp64 finalize)
__global__ __launch_bounds__(256) void k_redf(const float* __restrict__ part, int N, int nch,
    fp32p g, fp32p be, double cnt, float* __restrict__ sc, float* __restrict__ sh){
  __shared__ double sm[4];
  int c = blockIdx.x;
  double s=0.0, q=0.0;
  for (int i=threadIdx.x;i<N;i+=256){ s += (double)part[c*N+i]; q += (double)part[(nch+c)*N+i]; }
  s = block_sum_all_d(s, sm); __syncthreads();
  q = block_sum_all_d(q, sm);
  if (threadIdx.x==0){
    double m = s/cnt;
    double var = q/cnt - m*m;
    double sd = (double)g[c] / sqrt(var + 1e-5);
    sc[c] = (float)sd;
    sh[c] = (float)((double)be[c] - m*sd);
  }
}

// ---------------- reduce partials -> double scale/shift (BN2, argmin-critical)
__global__ __launch_bounds__(256) void k_redd(const float* __restrict__ part, int N, int nch,
    fp32p g, fp32p be, double cnt, double* __restrict__ sc, double* __restrict__ sh){
  __shared__ double sm[4];
  int c = blockIdx.x;
  double s=0.0, q=0.0;
  for (int i=threadIdx.x;i<N;i+=256){ s += (double)part[c*N+i]; q += (double)part[(nch+c)*N+i]; }
  s = block_sum_all_d(s, sm); __syncthreads();
  q = block_sum_all_d(q, sm);
  if (threadIdx.x==0){
    double m = s/cnt;
    double var = q/cnt - m*m;
    double sd = (double)g[c] / sqrt(var + 1e-5);
    sc[c] = sd;
    sh[c] = (double)be[c] - m*sd;
  }
}

// ---------------- K2: BN1+ReLU fused read, conv2 16->4 k4 s2 p1 + fused stats partials
__global__ __launch_bounds__(256) void k_conv2(const float* __restrict__ h1, fp32p w2, fp32p b2,
    const float* __restrict__ sc1, const float* __restrict__ sh1,
    float* __restrict__ h2, float* __restrict__ part){
  __shared__ float sw[16][16][4];   // [tap][ci][co]
  __shared__ float sb[4];
  __shared__ float red[4][8];
  int tid = threadIdx.x;
  for (int j=tid;j<1024;j+=256){
    int co=j&3, ci=(j>>2)&15, tap=j>>6;
    sw[tap][ci][co] = w2[(co*16+ci)*16 + tap];
  }
  if (tid<4) sb[tid]=b2[tid];
  __syncthreads();
  float sc[16], sh[16];
  #pragma unroll
  for (int c=0;c<16;c++){ sc[c]=sc1[c]; sh[c]=sh1[c]; }
  int gid = blockIdx.x*256+tid;
  int ox = gid&63, oy=(gid>>6)&63, n=gid>>12;
  float4 acc = *(float4*)&sb[0];
  #pragma unroll
  for (int ky=0;ky<4;ky++){
    int iy = oy*2-1+ky;
    if ((unsigned)iy >= 128u) continue;
    #pragma unroll
    for (int kx=0;kx<4;kx++){
      int ix = ox*2-1+kx;
      if ((unsigned)ix >= 128u) continue;
      const float4* hp = (const float4*)&h1[((n*128+iy)*128+ix)*16];
      const float4* wt = (const float4*)&sw[ky*4+kx][0][0];
      #pragma unroll
      for (int c4=0;c4<4;c4++){
        float4 hv = hp[c4];
        float v;
        v = fmaxf(fmaf(hv.x, sc[c4*4+0], sh[c4*4+0]), 0.f); acc = f4fma(v, wt[c4*4+0], acc);
        v = fmaxf(fmaf(hv.y, sc[c4*4+1], sh[c4*4+1]), 0.f); acc = f4fma(v, wt[c4*4+1], acc);
        v = fmaxf(fmaf(hv.z, sc[c4*4+2], sh[c4*4+2]), 0.f); acc = f4fma(v, wt[c4*4+2], acc);
        v = fmaxf(fmaf(hv.w, sc[c4*4+3], sh[c4*4+3]), 0.f); acc = f4fma(v, wt[c4*4+3], acc);
      }
    }
  }
  *(float4*)&h2[(unsigned)gid*4u] = acc;
  float aa[4]; *(float4*)&aa[0] = acc;
  int lane = tid & 63, wid = tid >> 6;
  #pragma unroll
  for (int c=0;c<4;c++){
    float s = aa[c], q = aa[c]*aa[c];
    #pragma unroll
    for (int m=1;m<64;m<<=1){ s += __shfl_xor(s,m,64); q += __shfl_xor(q,m,64); }
    if (lane==0){ red[wid][c]=s; red[wid][4+c]=q; }
  }
  __syncthreads();
  if (tid<8){
    float v = red[0][tid]+red[1][tid]+red[2][tid]+red[3][tid];
    part[tid*1024 + blockIdx.x] = v;
  }
}

// ---------------- K3: BN2(d)+ReLU -> pre 1x1 -> VQ argmin (fp64) -> loss -> post 1x1 -> di
__global__ __launch_bounds__(256) void k_vq(const float* __restrict__ h2,
    const double* __restrict__ bnd,
    fp32p wpre, fp32p bpre, fp32p emb, fp32p wpost, fp32p bpost,
    float* __restrict__ di, double* __restrict__ redE){
  __shared__ double se[128];
  __shared__ double sm[4];
  int tid = threadIdx.x;
  if (tid < 128) se[tid] = (double)emb[tid];
  __syncthreads();
  double sc[4], sh[4];
  #pragma unroll
  for (int c=0;c<4;c++){ sc[c]=bnd[c]; sh[c]=bnd[4+c]; }
  double wa0=wpre[0], wa1=wpre[1], wa2=wpre[2], wa3=wpre[3];
  double wb0=wpre[4], wb1=wpre[5], wb2=wpre[6], wb3=wpre[7];
  double bp0=bpre[0], bp1=bpre[1];
  double p00=wpost[0], p01=wpost[1];
  double p10=wpost[2], p11=wpost[3];
  double p20=wpost[4], p21=wpost[5];
  double p30=wpost[6], p31=wpost[7];
  double bq0=bpost[0], bq1=bpost[1], bq2=bpost[2], bq3=bpost[3];
  int p = blockIdx.x*256 + tid;             // 262144 threads, 1 pixel each
  float4 hv = *(const float4*)&h2[(unsigned)p*4u];
  double h0 = fmax(fma((double)hv.x, sc[0], sh[0]), 0.0);
  double h1v = fmax(fma((double)hv.y, sc[1], sh[1]), 0.0);
  double h2v = fmax(fma((double)hv.z, sc[2], sh[2]), 0.0);
  double h3v = fmax(fma((double)hv.w, sc[3], sh[3]), 0.0);
  double z0 = bp0 + wa0*h0 + wa1*h1v + wa2*h2v + wa3*h3v;
  double z1 = bp1 + wb0*h0 + wb1*h1v + wb2*h2v + wb3*h3v;
  double best = 1e300; int bi = 0;
  #pragma unroll
  for (int k=0;k<64;k++){
    double d0 = z0 - se[2*k], d1 = z1 - se[2*k+1];
    double d = fma(d0,d0, d1*d1);
    if (d < best){ best = d; bi = k; }      // first-min tie rule == argmin
  }
  double qv0 = se[2*bi], qv1 = se[2*bi+1];
  double e0 = qv0-z0, e1 = qv1-z1;
  double lsum = fma(e0,e0, e1*e1);
  float4 o;
  o.x = (float)(fma(p00,qv0, fma(p01,qv1, bq0)));
  o.y = (float)(fma(p10,qv0, fma(p11,qv1, bq1)));
  o.z = (float)(fma(p20,qv0, fma(p21,qv1, bq2)));
  o.w = (float)(fma(p30,qv0, fma(p31,qv1, bq3)));
  *(float4*)&di[(unsigned)p*4u] = o;
  double tot = block_sum_all_d(lsum, sm);
  if (tid==0) redE[blockIdx.x] = tot;
}

// ---------------- K4: BN3 stats via convT1 recompute, 2 px/thread (even,odd x-pair),
// wave-uniform oy -> broadcast weights; shared di loads (3 per row for 2 px).
__global__ __launch_bounds__(256) void k_stats3v2(const float* __restrict__ di, fp32p wd1, fp32p bd1,
                                                  float* __restrict__ part){
  __shared__ float sw[16][4][16];   // [tap][ci][co]
  __shared__ float sb[16];
  __shared__ float red[4][32];
  int tid = threadIdx.x;
  for (int j=tid; j<1024; j+=256){
    int co = j & 15, ci = (j>>4)&3, tap = j>>6;
    sw[tap][ci][co] = wd1[(ci*16+co)*16 + tap];
  }
  if (tid<16) sb[tid] = bd1[tid];
  __syncthreads();
  int gid = blockIdx.x*256 + tid;          // 2048 blocks: 64 xpair x 128 y x 64 n
  int k  = gid & 63;                       // = lane -> coalesced ix
  int oy = (gid >> 6) & 127;               // wave-uniform
  int n  = gid >> 13;
  float4 e0 = *(float4*)&sb[0], e1 = *(float4*)&sb[4],
         e2 = *(float4*)&sb[8], e3 = *(float4*)&sb[12];
  float4 o0 = e0, o1 = e1, o2 = e2, o3 = e3;
  int py = (oy+1)&1;                       // wave-uniform
  #pragma unroll
  for (int jt=0;jt<2;jt++){
    int ky = py + 2*jt;
    int iy = (oy+1-ky) >> 1;
    if ((unsigned)iy >= 64u) continue;     // uniform branch
    const float4* drow = (const float4*)&di[((n*64+iy)*64)*4];
    float4 dm = (k>=1) ? drow[k-1] : make_float4(0.f,0.f,0.f,0.f);
    float4 d0 = drow[k];
    float4 dp = (k<63) ? drow[k+1] : make_float4(0.f,0.f,0.f,0.f);
    // even px (ox=2k, pxx=1): it=0 -> kx=1 (ix=k, d0); it=1 -> kx=3 (ix=k-1, dm)
    {
      int tap = ky*4 + 1;
      float vv[4] = {d0.x, d0.y, d0.z, d0.w};
      #pragma unroll
      for (int ci=0;ci<4;ci++){
        const float4* wr = (const float4*)&sw[tap][ci][0];
        e0 = f4fma(vv[ci], wr[0], e0); e1 = f4fma(vv[ci], wr[1], e1);
        e2 = f4fma(vv[ci], wr[2], e2); e3 = f4fma(vv[ci], wr[3], e3);
      }
      tap = ky*4 + 3;
      float vm[4] = {dm.x, dm.y, dm.z, dm.w};
      #pragma unroll
      for (int ci=0;ci<4;ci++){
        const float4* wr = (const float4*)&sw[tap][ci][0];
        e0 = f4fma(vm[ci], wr[0], e0); e1 = f4fma(vm[ci], wr[1], e1);
        e2 = f4fma(vm[ci], wr[2], e2); e3 = f4fma(vm[ci], wr[3], e3);
      }
    }
    // odd px (ox=2k+1, pxx=0): it=0 -> kx=0 (ix=k+1, dp); it=1 -> kx=2 (ix=k, d0)
    {
      int tap = ky*4 + 0;
      float vp[4] = {dp.x, dp.y, dp.z, dp.w};
      #pragma unroll
      for (int ci=0;ci<4;ci++){
        const float4* wr = (const float4*)&sw[tap][ci][0];
        o0 = f4fma(vp[ci], wr[0], o0); o1 = f4fma(vp[ci], wr[1], o1);
        o2 = f4fma(vp[ci], wr[2], o2); o3 = f4fma(vp[ci], wr[3], o3);
      }
      tap = ky*4 + 2;
      float v0[4] = {d0.x, d0.y, d0.z, d0.w};
      #pragma unroll
      for (int ci=0;ci<4;ci++){
        const float4* wr = (const float4*)&sw[tap][ci][0];
        o0 = f4fma(v0[ci], wr[0], o0); o1 = f4fma(v0[ci], wr[1], o1);
        o2 = f4fma(v0[ci], wr[2], o2); o3 = f4fma(v0[ci], wr[3], o3);
      }
    }
  }
  float fe[16], fo[16];
  *(float4*)&fe[0]=e0; *(float4*)&fe[4]=e1; *(float4*)&fe[8]=e2; *(float4*)&fe[12]=e3;
  *(float4*)&fo[0]=o0; *(float4*)&fo[4]=o1; *(float4*)&fo[8]=o2; *(float4*)&fo[12]=o3;
  int lane = tid & 63, wid = tid >> 6;
  #pragma unroll
  for (int c=0;c<16;c++){
    float s = fe[c] + fo[c];
    float q = fmaf(fe[c],fe[c], fo[c]*fo[c]);
    #pragma unroll
    for (int m=1;m<64;m<<=1){ s += __shfl_xor(s,m,64); q += __shfl_xor(q,m,64); }
    if (lane==0){ red[wid][c]=s; red[wid][16+c]=q; }
  }
  __syncthreads();
  if (tid<32){
    float v = red[0][tid]+red[1][tid]+red[2][tid]+red[3][tid];
    part[tid*2048 + blockIdx.x] = v;
  }
}

// ---------------- K5: fused convT1 -> BN3+ReLU (LDS) -> convT2 -> tanh -> out + recon loss
// Phase A: wave-uniform parity classes. Phase B: q-major shared-column loads.
__global__ __launch_bounds__(256) void k_fuseT8(const float* __restrict__ di,
    fp32p wd1, fp32p bd1, fp32p wd2, fp32p bd2,
    const float* __restrict__ sc3, const float* __restrict__ sh3,
    fp32p x, float* __restrict__ out, double* __restrict__ redH){
  __shared__ float swt[1024];  // convT1 weights [ky][kx][ci4][co16]
  __shared__ float sb1[16];
  __shared__ float sw2[256];   // convT2 weights [ky][kx][ci16]
  __shared__ float h3q[4][18][19][4];
  __shared__ double smd[4];
  int tid = threadIdx.x;
  for (int j=tid; j<1024; j+=256){
    int co = j & 15, ci = (j>>4)&3, kx = (j>>6)&3, ky = j>>8;
    swt[j] = wd1[((ci*16+co)*4+ky)*4+kx];
  }
  { int ci = tid & 15, kx = (tid>>4)&3, ky = tid>>6;
    sw2[tid] = wd2[ci*16 + ky*4 + kx]; }
  if (tid<16) sb1[tid] = bd1[tid];
  float s3[16], h3s[16];
  #pragma unroll
  for (int c=0;c<16;c++){ s3[c]=sc3[c]; h3s[c]=sh3[c]; }
  int b = blockIdx.x;
  int n = b>>6, ty=(b>>3)&7, tx=b&7;
  int OY=ty*32, OX=tx*32;
  int R0=ty*16-1, C0=tx*16-1;
  __syncthreads();
  // Phase A: 18x18 h3 tile by wave-uniform parity class: cls = tid>>6 (one class/wave)
  int clsA = tid >> 6;
  int prA = clsA >> 1, pcA = clsA & 1;
  for (int it2=0; it2<2; it2++){
    int idx = (tid & 63) + it2*64;
    if (idx < 81){
      int u = idx/9, v = idx - u*9;
      int rr = 2*u + prA, cc = 2*v + pcA;
      int r = R0 + rr, c = C0 + cc;
      float vo[16];
      if ((unsigned)r < 128u && (unsigned)c < 128u){
        float acc[16];
        #pragma unroll
        for (int ch=0;ch<16;ch++) acc[ch]=sb1[ch];
        #pragma unroll
        for (int j=0;j<2;j++){
          int iy = ty*8 + u - j;
          if ((unsigned)iy >= 64u) continue;
          #pragma unroll
          for (int i=0;i<2;i++){
            int ix = tx*8 + v - i;
            if ((unsigned)ix >= 64u) continue;
            float4 dv = *(const float4*)&di[((n*64+iy)*64+ix)*4];
            const float* wb = &swt[(((prA+2*j)*4+(pcA+2*i))*4)*16];  // broadcast
            float vv[4] = {dv.x, dv.y, dv.z, dv.w};
            #pragma unroll
            for (int ci=0;ci<4;ci++){
              #pragma unroll
              for (int co=0;co<16;co++)
                acc[co] = fmaf(vv[ci], wb[ci*16+co], acc[co]);
            }
          }
        }
        #pragma unroll
        for (int ch=0;ch<16;ch++) vo[ch] = fmaxf(fmaf(acc[ch], s3[ch], h3s[ch]), 0.f);
      } else {
        #pragma unroll
        for (int ch=0;ch<16;ch++) vo[ch]=0.f;
      }
      #pragma unroll
      for (int q=0;q<4;q++)
        *(float4*)&h3q[q][rr][cc][0] = make_float4(vo[4*q],vo[4*q+1],vo[4*q+2],vo[4*q+3]);
    }
  }
  __syncthreads();
  // Phase B: q-major, shared columns.
  int lane = tid & 63, wv = tid >> 6;
  int ri = lane >> 3, tc = lane & 7;
  int row = (wv>>1)*16 + ri*2 + (wv&1);
  int oy = OY + row, ox0 = OX + tc*4;
  int py = (oy+1)&1;                        // wave-uniform
  int rr0 = ((oy + 1 - py) >> 1) - R0;      // in [1,17]; rr0-1 in [0,16]
  int c0 = tc*2;
  float bias = bd2[0];
  float a0=bias, a1=bias, a2=bias, a3=bias;
  #pragma unroll
  for (int q=0;q<4;q++){
    #pragma unroll
    for (int j=0;j<2;j++){
      int rr = rr0 - j;
      int kyb = (py + 2*j)*4;
      float4 d0 = *(float4*)&h3q[q][rr][c0+0][0];
      float4 d1 = *(float4*)&h3q[q][rr][c0+1][0];
      float4 d2 = *(float4*)&h3q[q][rr][c0+2][0];
      float4 d3 = *(float4*)&h3q[q][rr][c0+3][0];
      {
        float4 wA = *(float4*)&sw2[(kyb+1)*16 + q*4];   // broadcast
        float4 wB = *(float4*)&sw2[(kyb+3)*16 + q*4];
        a0 = dot4acc(d1, wA, a0); a0 = dot4acc(d0, wB, a0);
        a2 = dot4acc(d2, wA, a2); a2 = dot4acc(d1, wB, a2);
      }
      {
        float4 wA = *(float4*)&sw2[(kyb+0)*16 + q*4];
        float4 wB = *(float4*)&sw2[(kyb+2)*16 + q*4];
        a1 = dot4acc(d2, wA, a1); a1 = dot4acc(d1, wB, a1);
        a3 = dot4acc(d3, wA, a3); a3 = dot4acc(d2, wB, a3);
      }
    }
  }
  int base = (n*256+oy)*256 + ox0;
  float4 xv = *(const float4*)&x[base];
  float av[4] = {a0,a1,a2,a3};
  float r4[4];
  double rsum = 0.0;
  #pragma unroll
  for (int k=0;k<4;k++){
    float e = __expf(2.f*av[k]);
    float t = 1.f - 2.f/(e+1.f);            // tanh
    r4[k] = t;
    float xd = (k==0?xv.x:k==1?xv.y:k==2?xv.z:xv.w);
    double dd = (double)xd - (double)t;
    rsum = fma(dd,dd,rsum);
  }
  *(float4*)&out[base] = make_float4(r4[0],r4[1],r4[2],r4[3]);
  double tot = block_sum_all_d(rsum, smd);
  if (tid==0) redH[b] = tot;
}

// ---------------- K6: finalize loss
__global__ __launch_bounds__(256) void k_final(const double* __restrict__ redE, const double* __restrict__ redH,
                                               float* __restrict__ out, int out_size){
  __shared__ double sm[4];
  int tid = threadIdx.x;
  double a = 0.0;
  for (int i=tid;i<1024;i+=256) a += redE[i];
  double b = 0.0;
  for (int i=tid;i<4096;i+=256) b += redH[i];
  double ta = block_sum_all_d(a, sm);
  __syncthreads();
  double tb = block_sum_all_d(b, sm);
  if (tid==0){
    double loss = 1.2*ta/524288.0 + tb/4194304.0;  // (1+BETA)*mean((q-z)^2) + recon_mean
    out[out_size-1] = (float)loss;
  }
}

extern "C" void kernel_launch(void* const* d_in, const int* in_sizes, int n_in,
                              void* d_out, int out_size, void* d_ws, size_t ws_size,
                              hipStream_t stream) {
  (void)ws_size;
  int I[20];
  for (int i=0;i<20;i++) I[i]=i;
  if (n_in >= 20 && in_sizes[0] != 4194304 && in_sizes[19] == 4194304){
    static const int remap[20] = {19,13,0,10,4,14,1,11,5,18,8,9,17,7,15,2,12,6,16,3};
    for (int i=0;i<20;i++) I[i]=remap[i];
  }
  fp32p x    = (fp32p)d_in[I[0]];
  fp32p w1   = (fp32p)d_in[I[1]],  b1 = (fp32p)d_in[I[2]],  g1 = (fp32p)d_in[I[3]],  be1 = (fp32p)d_in[I[4]];
  fp32p w2   = (fp32p)d_in[I[5]],  b2 = (fp32p)d_in[I[6]],  g2 = (fp32p)d_in[I[7]],  be2 = (fp32p)d_in[I[8]];
  fp32p wpre = (fp32p)d_in[I[9]],  bpre = (fp32p)d_in[I[10]], emb = (fp32p)d_in[I[11]];
  fp32p wpost= (fp32p)d_in[I[12]], bpost= (fp32p)d_in[I[13]];
  fp32p wd1  = (fp32p)d_in[I[14]], bd1 = (fp32p)d_in[I[15]], g3 = (fp32p)d_in[I[16]], be3 = (fp32p)d_in[I[17]];
  fp32p wd2  = (fp32p)d_in[I[18]], bd2 = (fp32p)d_in[I[19]];

  char* wsb = (char*)d_ws;
  float* h1    = (float*)(wsb);
  float* h2    = (float*)(wsb + 67108864);
  float* di    = (float*)(wsb + 71303168);
  float* bnf   = (float*)(wsb + 75497472);         // sc1,sh1,sc3,sh3
  double* bnd  = (double*)(wsb + 75497728);        // sc2d[4], sh2d[4]
  double* redE = (double*)(wsb + 75497792);        // 1024 doubles
  double* redH = (double*)(wsb + 67108864);        // aliases h2 (dead after vq)
  float* part1 = (float*)(wsb + 67108864);         // aliases h2 (consumed before conv2 writes)
  float* part2 = (float*)(wsb + 71303168);         // aliases di (consumed before vq writes)
  float* part3 = (float*)(wsb);                    // aliases h1 (h1 dead after conv2)
  float* sc1 = bnf, *sh1 = bnf+16, *sc3 = bnf+32, *sh3 = bnf+48;
  float* out = (float*)d_out;

  k_conv1v2 <<<2048,256,0,stream>>>(x, w1, b1, h1, part1);
  k_redf    <<<16,256,0,stream>>>(part1, 2048, 16, g1, be1, 1048576.0, sc1, sh1);
  k_conv2   <<<1024,256,0,stream>>>(h1, w2, b2, sc1, sh1, h2, part2);
  k_redd    <<<4,256,0,stream>>>(part2, 1024, 4, g2, be2, 262144.0, bnd, bnd+4);
  k_vq      <<<1024,256,0,stream>>>(h2, bnd, wpre, bpre, emb, wpost, bpost, di, redE);
  k_stats3v2<<<2048,256,0,stream>>>(di, wd1, bd1, part3);
  k_redf    <<<16,256,0,stream>>>(part3, 2048, 16, g3, be3, 1048576.0, sc3, sh3);
  k_fuseT8  <<<4096,256,0,stream>>>(di, wd1, bd1, wd2, bd2, sc3, sh3, x, out, redH);
  k_final   <<<1,256,0,stream>>>(redE, redH, out, out_size);
}